// Round 6
// baseline (153.641 us; speedup 1.0000x reference)
//
#include <hip/hip_runtime.h>

// ConvByMoveLayer: out[b,f,o] = sum_m sum_c x[b, mask[m,f], c] * W[m,c,o] + bias[f,o]
// B=128, F=4096, C=32, O=32, M=9.
//
// Round 6: amortize + pipeline pass2.
//   Round 5's XCD-local gather (xh2[bslice][f][b'][c], blk%8 = XCD) stays.
//   New: 512 blocks (8 XCD x 64); block covers 64 fields; wave loops 8 iters
//   of a 2-field x 16-batch MFMA tile with DOUBLE-BUFFERED A-fragments
//   (prefetch iter+1's 18 gathers under iter's 18 MFMAs). Weights (18 KB) and
//   masks (2.3 KB) staged in LDS once per block: staging traffic 73 MB -> 11 MB.
//   __launch_bounds__(256,2) so a[2][18] (144 VGPR) stays in registers.

#define B_ 128
#define F_ 4096
#define C_ 32
#define O_ 32
#define M_ 9
#define T_ 18          // K=16 MFMA slices (M_*C_/16)
#define TF1 32         // fields per pass1 block
#define LROW1 528      // padded LDS row (halfs)
#define FPB2 64        // fields per pass2 block
#define NIT 8          // iterations per wave (2 fields each, 4 waves)

typedef _Float16 halfx4 __attribute__((ext_vector_type(4)));
typedef _Float16 halfx8 __attribute__((ext_vector_type(8)));
typedef float floatx4 __attribute__((ext_vector_type(4)));
typedef float floatx16 __attribute__((ext_vector_type(16)));

// ---------------- Pass 1: slice-transpose + convert, build W fragments ----------------
// grid: 8 * (F_/TF1) blocks; blk%8 = bslice (XCD), blk/8 = field tile.
__global__ __launch_bounds__(256) void pass1_transpose(
    const float* __restrict__ x, const float* __restrict__ coeffs,
    _Float16* __restrict__ xh, _Float16* __restrict__ wf)
{
    __shared__ _Float16 tile[TF1 * LROW1];
    const int blk = blockIdx.x;
    const int bs  = blk & 7;
    const int f0  = (blk >> 3) * TF1;
    const int tid = threadIdx.x;

    // Read phase: 16 iters over b'; 256 threads cover 32 f x 32 c fp32 = 4 KB run.
    {
        const int f_l = tid >> 3;
        const int c4  = (tid & 7) * 4;
        const float* src = x + ((size_t)f0 + f_l) * C_ + c4;
#pragma unroll
        for (int bp = 0; bp < 16; ++bp) {
            const floatx4* p = reinterpret_cast<const floatx4*>(
                src + (size_t)(bs * 16 + bp) * (F_ * C_));
            floatx4 v = __builtin_nontemporal_load(p);
            halfx4 hv;
            hv[0] = (_Float16)v[0]; hv[1] = (_Float16)v[1];
            hv[2] = (_Float16)v[2]; hv[3] = (_Float16)v[3];
            *reinterpret_cast<halfx4*>(&tile[f_l * LROW1 + bp * C_ + c4]) = hv;
        }
    }
    __syncthreads();

    // Write phase: per field, 16 b' x 32 c fp16 = 1 KB contiguous per wave.
    {
        const int wv   = tid >> 6;
        const int lane = tid & 63;
#pragma unroll
        for (int it = 0; it < TF1 / 4; ++it) {
            int f_l = it * 4 + wv;
            halfx8 v = *reinterpret_cast<const halfx8*>(&tile[f_l * LROW1 + lane * 8]);
            *reinterpret_cast<halfx8*>(
                xh + ((size_t)bs * F_ + f0 + f_l) * (16 * C_) + lane * 8) = v;
        }
    }

    // Block 0 builds the B-fragment-ordered weight stack:
    // wf[t][lane][j] = W[m = t>>1][c = 16*(t&1) + 8*(lane>>5) + j][o = lane&31]
    if (blk == 0) {
        for (int id = tid; id < T_ * 64; id += 256) {
            int t  = id >> 6;
            int L  = id & 63;
            int m  = t >> 1;
            int cb = 16 * (t & 1) + 8 * (L >> 5);
            int o  = L & 31;
            halfx8 w;
#pragma unroll
            for (int j = 0; j < 8; ++j)
                w[j] = (_Float16)coeffs[(m * C_ + cb + j) * O_ + o];
            *reinterpret_cast<halfx8*>(wf + id * 8) = w;
        }
    }
}

// ---------------- Pass 2: XCD-local gather + pipelined MFMA GEMM ----------------
// grid: 8 * (F_/FPB2) = 512 blocks; blk%8 = bslice (XCD), blk/8 = field group.
// Wave: NIT iters x (2 fields x 16 batches), double-buffered A prefetch.
__global__ __launch_bounds__(256, 2) void pass2_gemm(
    const _Float16* __restrict__ xh, const _Float16* __restrict__ wf,
    const int* __restrict__ mask, const float* __restrict__ biases,
    float* __restrict__ out)
{
    __shared__ _Float16 sw[T_ * 64 * 8];    // 18 KB B-fragments
    __shared__ int smask[M_][FPB2];         // 2.3 KB gather indices
    const int tid = threadIdx.x;
    const int blk = blockIdx.x;
    const int bs  = blk & 7;                // batch slice == XCD (round-robin)
    const int f0  = (blk >> 3) * FPB2;

    for (int i = tid; i < T_ * 64; i += 256)
        reinterpret_cast<halfx8*>(sw)[i] = reinterpret_cast<const halfx8*>(wf)[i];
    for (int i = tid; i < M_ * FPB2; i += 256)
        smask[i >> 6][i & 63] = mask[(i >> 6) * F_ + f0 + (i & 63)];
    __syncthreads();

    const int wave = tid >> 6;
    const int lane = tid & 63;
    const int h    = lane >> 5;             // K-half selector
    const int row  = lane & 31;             // MFMA M-row = fi*16 + b'
    const int fi   = row >> 4;
    const int bp   = row & 15;
    const int ocol = lane & 31;             // C/D col = output channel

    // Slice base: xh2[bs][s][b'][c], s-stride = 16*C_ halfs.
    const _Float16* xb = xh + (size_t)bs * F_ * (16 * C_) + bp * C_ + 8 * h;

    halfx8 a[2][T_];
    // Prologue: gather iteration 0.
    {
        const int floc = 2 * wave + fi;
#pragma unroll
        for (int m = 0; m < M_; ++m) {
            const _Float16* rp = xb + (size_t)smask[m][floc] * (16 * C_);
            a[0][2 * m]     = *reinterpret_cast<const halfx8*>(rp);
            a[0][2 * m + 1] = *reinterpret_cast<const halfx8*>(rp + 16);
        }
    }

#pragma unroll
    for (int it = 0; it < NIT; ++it) {
        const int cur = it & 1;
        if (it + 1 < NIT) {                 // prefetch next iteration's A
            const int floc = (it + 1) * 8 + 2 * wave + fi;
#pragma unroll
            for (int m = 0; m < M_; ++m) {
                const _Float16* rp = xb + (size_t)smask[m][floc] * (16 * C_);
                a[cur ^ 1][2 * m]     = *reinterpret_cast<const halfx8*>(rp);
                a[cur ^ 1][2 * m + 1] = *reinterpret_cast<const halfx8*>(rp + 16);
            }
        }
        floatx16 acc;
#pragma unroll
        for (int i = 0; i < 16; ++i) acc[i] = 0.0f;
#pragma unroll
        for (int t = 0; t < T_; ++t) {
            halfx8 bwt = *reinterpret_cast<const halfx8*>(&sw[(t * 64 + lane) * 8]);
            acc = __builtin_amdgcn_mfma_f32_32x32x16_f16(a[cur][t], bwt, acc, 0, 0, 0);
        }
        const int fa = f0 + it * 8 + 2 * wave;   // this wave-iter's field pair
        float bias_a = biases[(size_t)fa * O_ + ocol];
        float bias_b = biases[(size_t)(fa + 1) * O_ + ocol];
        // C/D layout (m74/m101): col = lane&31, row = (r&3)+8*(r>>2)+4*(lane>>5)
#pragma unroll
        for (int r = 0; r < 16; ++r) {
            int orow = (r & 3) + 8 * (r >> 2) + 4 * h;
            int ofi  = orow >> 4;
            int b    = bs * 16 + (orow & 15);
            float v  = acc[r] + (ofi ? bias_b : bias_a);
            __builtin_nontemporal_store(
                v, &out[((size_t)b * F_ + fa + ofi) * O_ + ocol]);
        }
    }
}

// ---------------- Fallback (correct, slow) if ws too small ----------------
__global__ __launch_bounds__(256) void fallback_kernel(
    const float* __restrict__ x, const int* __restrict__ mask,
    const float* __restrict__ coeffs, const float* __restrict__ biases,
    float* __restrict__ out)
{
    int gid = blockIdx.x * 256 + threadIdx.x;   // over B*F*O
    int o = gid & (O_ - 1);
    int f = (gid >> 5) & (F_ - 1);
    int b = gid >> 17;
    float acc = biases[f * O_ + o];
    for (int m = 0; m < M_; ++m) {
        int s = mask[m * F_ + f];
        const float* xr = x + ((size_t)b * F_ + s) * C_;
        const float* wr = coeffs + (m * C_) * O_ + o;
#pragma unroll
        for (int c = 0; c < C_; ++c)
            acc += xr[c] * wr[c * O_];
    }
    out[gid] = acc;
}

extern "C" void kernel_launch(void* const* d_in, const int* in_sizes, int n_in,
                              void* d_out, int out_size, void* d_ws, size_t ws_size,
                              hipStream_t stream) {
    const float* x      = (const float*)d_in[0];
    const int*   mask   = (const int*)d_in[1];
    const float* coeffs = (const float*)d_in[2];
    const float* biases = (const float*)d_in[3];
    float* out = (float*)d_out;

    const size_t xh_elems = (size_t)B_ * F_ * C_;
    const size_t need = xh_elems * sizeof(_Float16) + (size_t)T_ * 64 * 8 * sizeof(_Float16);

    if (ws_size >= need) {
        _Float16* xh = (_Float16*)d_ws;
        _Float16* wf = xh + xh_elems;
        pass1_transpose<<<8 * (F_ / TF1), 256, 0, stream>>>(x, coeffs, xh, wf);
        pass2_gemm<<<8 * (F_ / FPB2), 256, 0, stream>>>(xh, wf, mask, biases, out);
    } else {
        fallback_kernel<<<(B_ * F_ * O_) / 256, 256, 0, stream>>>(x, mask, coeffs, biases, out);
    }
}